// Round 1
// baseline (1681.415 us; speedup 1.0000x reference)
//
#include <hip/hip_runtime.h>
#include <hip/hip_bf16.h>
#include <cmath>
#include <cstdint>

typedef __bf16 bf16_t;
typedef bf16_t bf16x8 __attribute__((ext_vector_type(8)));
typedef bf16_t bf16x4 __attribute__((ext_vector_type(4)));
typedef float f32x4 __attribute__((ext_vector_type(4)));

#define BB 2
#define LL 2048
#define DMODEL 1024
#define DINNER 2048
#define DSTATE 16

// ---------------- fp32 -> bf16 convert (4 elems/thread) ----------------
__global__ void k_cvt4(const float* __restrict__ in, bf16_t* __restrict__ out, int n4) {
    int i = blockIdx.x * 256 + threadIdx.x;
    if (i >= n4) return;
    float4 v = reinterpret_cast<const float4*>(in)[i];
    bf16x4 o;
    o[0] = (bf16_t)v.x; o[1] = (bf16_t)v.y; o[2] = (bf16_t)v.z; o[3] = (bf16_t)v.w;
    reinterpret_cast<bf16x4*>(out)[i] = o;
}

// ---------------- W_xp [96,2048] -> bf16 zero-padded [128,2048] ----------------
__global__ void k_cvt_wxp(const float* __restrict__ in, bf16_t* __restrict__ out) {
    int i = blockIdx.x * 256 + threadIdx.x;   // over 128*2048
    int r = i >> 11, c = i & (DINNER - 1);
    float v = (r < 96) ? in[r * DINNER + c] : 0.f;
    out[i] = (bf16_t)v;
}

// ---------------- async global->LDS helper ----------------
__device__ __forceinline__ void gload16(const void* g, void* l) {
    __builtin_amdgcn_global_load_lds(
        (const __attribute__((address_space(1))) void*)g,
        (__attribute__((address_space(3))) void*)l,
        16, 0, 0);
}

enum { EPI_F32 = 0, EPI_BF16 = 1, EPI_BIAS = 2, EPI_SOFTPLUS = 3, EPI_SPLIT = 4 };

// ---------------- bf16 MFMA GEMM: C[M,N] = A[M,K] @ B[N,K]^T ----------------
// 128x128 tile, BK=32, 256 threads = 4 waves (2x2 of 64x64), 16x16x32 bf16 MFMA.
template <int EPI>
__global__ void k_gemm_bt(const bf16_t* __restrict__ A, const bf16_t* __restrict__ Bt,
                          int M, int N, int K,
                          float* __restrict__ C, bf16_t* __restrict__ Cb,
                          const float* __restrict__ bias,
                          bf16_t* __restrict__ o_dtr, float* __restrict__ o_B,
                          float* __restrict__ o_C) {
    __shared__ bf16_t sA[128 * 32];
    __shared__ bf16_t sB[128 * 32];
    const int tid = threadIdx.x;
    const int wid = tid >> 6, lane = tid & 63;
    const int ntile = N >> 7;
    const int m0 = (blockIdx.x / ntile) << 7;
    const int n0 = (blockIdx.x % ntile) << 7;
    const int wr = wid >> 1, wc = wid & 1;
    f32x4 acc[4][4] = {};

    // staging: thread tid fills 16B chunk tid (and tid+256); chunk -> row=chunk/4, k8=chunk%4
    const bf16_t* ap = A + (size_t)(m0 + (tid >> 2)) * K + (tid & 3) * 8;
    const bf16_t* bp = Bt + (size_t)(n0 + (tid >> 2)) * K + (tid & 3) * 8;
    char* sAd = (char*)sA + wid * 1024;   // wave-uniform LDS dst (lane*16 added by HW)
    char* sBd = (char*)sB + wid * 1024;

    const int lm = lane & 15, lk = (lane >> 4) * 8;
    const bf16_t* rA = sA + (wr * 64 + lm) * 32 + lk;
    const bf16_t* rB = sB + (wc * 64 + lm) * 32 + lk;

    for (int kt = 0; kt < K; kt += 32) {
        __syncthreads();
        gload16(ap + kt, sAd);
        gload16(ap + kt + (size_t)64 * K, sAd + 4096);
        gload16(bp + kt, sBd);
        gload16(bp + kt + (size_t)64 * K, sBd + 4096);
        __syncthreads();
        bf16x8 fa[4], fb[4];
        #pragma unroll
        for (int i = 0; i < 4; ++i) fa[i] = *(const bf16x8*)(rA + i * 16 * 32);
        #pragma unroll
        for (int j = 0; j < 4; ++j) fb[j] = *(const bf16x8*)(rB + j * 16 * 32);
        #pragma unroll
        for (int i = 0; i < 4; ++i)
            #pragma unroll
            for (int j = 0; j < 4; ++j)
                acc[i][j] = __builtin_amdgcn_mfma_f32_16x16x32_bf16(fa[i], fb[j], acc[i][j], 0, 0, 0);
    }

    // C/D layout (m89-verified): col = lane&15, row = (lane>>4)*4 + reg
    const int row0 = m0 + wr * 64 + (lane >> 4) * 4;
    const int col0 = n0 + wc * 64 + lm;
    #pragma unroll
    for (int i = 0; i < 4; ++i) {
        #pragma unroll
        for (int j = 0; j < 4; ++j) {
            #pragma unroll
            for (int r = 0; r < 4; ++r) {
                int row = row0 + i * 16 + r;
                int c = col0 + j * 16;
                float v = acc[i][j][r];
                if (EPI == EPI_F32) {
                    C[(size_t)row * N + c] = v;
                } else if (EPI == EPI_BF16) {
                    Cb[(size_t)row * N + c] = (bf16_t)v;
                } else if (EPI == EPI_BIAS) {
                    C[(size_t)row * N + c] = v + bias[c];
                } else if (EPI == EPI_SOFTPLUS) {
                    float xv = v + bias[c];
                    C[(size_t)row * N + c] = fmaxf(xv, 0.f) + log1pf(__expf(-fabsf(xv)));
                } else {  // EPI_SPLIT: cols [0,64)->dtr bf16, [64,80)->B f32, [80,96)->C f32
                    if (c < 64) o_dtr[(size_t)row * 64 + c] = (bf16_t)v;
                    else if (c < 80) o_B[(size_t)row * 16 + (c - 64)] = v;
                    else if (c < 96) o_C[(size_t)row * 16 + (c - 80)] = v;
                }
            }
        }
    }
}

// ---------------- causal depthwise conv (k=4) + bias + SiLU ----------------
__global__ void k_conv(const float* __restrict__ xz, const float* __restrict__ cw,
                       const float* __restrict__ cb, float* __restrict__ xs,
                       bf16_t* __restrict__ xs_b) {
    int idx = blockIdx.x * 256 + threadIdx.x;   // over B*L*DINNER
    int d = idx & (DINNER - 1);
    int bl = idx >> 11;
    int l = bl & (LL - 1);
    const float* col = xz + (size_t)(bl - l) * (2 * DINNER) + d;  // batch base, xin part
    float acc = cb[d];
    #pragma unroll
    for (int j = 0; j < 4; ++j) {
        int li = l - 3 + j;
        if (li >= 0) acc += cw[d * 4 + j] * col[(size_t)li * (2 * DINNER)];
    }
    float s = acc / (1.f + __expf(-acc));
    xs[idx] = s;
    xs_b[idx] = (bf16_t)s;
}

// ---------------- selective scan + D-skip + z-gate, writes y as bf16 ----------------
// lane: s = lane&15 (state), c = lane>>4 (channel-in-group); wave owns 4 channels.
__global__ __launch_bounds__(256) void k_scan(
    const float* __restrict__ dt,    // [B,L,DI]
    const float* __restrict__ xs,    // [B,L,DI]
    const float* __restrict__ Bm,    // [B,L,16]
    const float* __restrict__ Cm,    // [B,L,16]
    const float* __restrict__ xz,    // z at col DI.. of 4096-wide rows
    const float* __restrict__ A_log, // [DI,16]
    const float* __restrict__ Dp,    // [DI]
    bf16_t* __restrict__ y) {        // [B*L, DI]
    const int tid = threadIdx.x;
    const int wave = tid >> 6, lane = tid & 63;
    const int s = lane & 15, c = lane >> 4;
    const int b = blockIdx.x >> 7;       // 128 groups per batch
    const int g = blockIdx.x & 127;
    const int d = g * 16 + wave * 4 + c;

    const float a = -__expf(A_log[d * DSTATE + s]);
    const float Dd = Dp[d];
    const float* dtp = dt + (size_t)b * LL * DINNER + d;
    const float* xsp = xs + (size_t)b * LL * DINNER + d;
    const float* Bp = Bm + (size_t)b * LL * DSTATE + s;
    const float* Cp = Cm + (size_t)b * LL * DSTATE + s;
    const float* zp = xz + (size_t)b * LL * (2 * DINNER) + DINNER + d;
    bf16_t* yp = y + (size_t)b * LL * DINNER + d;

    float h = 0.f;
    #pragma unroll 4
    for (int t = 0; t < LL; ++t) {
        float dtv = dtp[(size_t)t * DINNER];
        float xv  = xsp[(size_t)t * DINNER];
        float Bv  = Bp[(size_t)t * DSTATE];
        float Cv  = Cp[(size_t)t * DSTATE];
        float dA = __expf(dtv * a);
        h = fmaf(h, dA, dtv * xv * Bv);
        float p = h * Cv;
        p += __shfl_xor(p, 1, 16);
        p += __shfl_xor(p, 2, 16);
        p += __shfl_xor(p, 4, 16);
        p += __shfl_xor(p, 8, 16);
        if (s == 0) {
            float zv = zp[(size_t)t * (2 * DINNER)];
            float yv = (p + xv * Dd) * (zv / (1.f + __expf(-zv)));
            yp[(size_t)t * DINNER] = (bf16_t)yv;
        }
    }
}

extern "C" void kernel_launch(void* const* d_in, const int* in_sizes, int n_in,
                              void* d_out, int out_size, void* d_ws, size_t ws_size,
                              hipStream_t stream) {
    const float* x      = (const float*)d_in[0];
    const float* W_in   = (const float*)d_in[1];
    const float* conv_w = (const float*)d_in[2];
    const float* conv_b = (const float*)d_in[3];
    const float* W_xp   = (const float*)d_in[4];
    const float* W_dt   = (const float*)d_in[5];
    const float* b_dt   = (const float*)d_in[6];
    const float* A_log  = (const float*)d_in[7];
    const float* Dvec   = (const float*)d_in[8];
    const float* W_os   = (const float*)d_in[9];
    const float* W_o    = (const float*)d_in[10];
    const float* b_o    = (const float*)d_in[11];
    float* out = (float*)d_out;

    char* base = (char*)d_ws;
    size_t off = 0;
    auto alloc = [&](size_t bytes) -> char* {
        char* p = base + off;
        off += (bytes + 255) & ~(size_t)255;
        return p;
    };
    const int MR = BB * LL;  // 4096 rows
    float*  xz    = (float*)alloc((size_t)MR * 4096 * 4);
    float*  xs    = (float*)alloc((size_t)MR * DINNER * 4);
    bf16_t* xs_b  = (bf16_t*)alloc((size_t)MR * DINNER * 2);
    float*  dt    = (float*)alloc((size_t)MR * DINNER * 4);
    bf16_t* dtr_b = (bf16_t*)alloc((size_t)MR * 64 * 2);
    float*  Bmf   = (float*)alloc((size_t)MR * 16 * 4);
    float*  Cmf   = (float*)alloc((size_t)MR * 16 * 4);
    bf16_t* y_b   = (bf16_t*)alloc((size_t)MR * DINNER * 2);
    bf16_t* y2_b  = (bf16_t*)alloc((size_t)MR * DMODEL * 2);
    bf16_t* x_b   = (bf16_t*)alloc((size_t)MR * DMODEL * 2);
    bf16_t* Win_b = (bf16_t*)alloc((size_t)4096 * 1024 * 2);
    bf16_t* Wxp_b = (bf16_t*)alloc((size_t)128 * DINNER * 2);
    bf16_t* Wdt_b = (bf16_t*)alloc((size_t)DINNER * 64 * 2);
    bf16_t* Wos_b = (bf16_t*)alloc((size_t)DMODEL * DINNER * 2);
    bf16_t* Wo_b  = (bf16_t*)alloc((size_t)DMODEL * DMODEL * 2);

    auto cvt = [&](const float* src, bf16_t* dst, size_t n) {
        int n4 = (int)(n / 4);
        k_cvt4<<<(n4 + 255) / 256, 256, 0, stream>>>(src, dst, n4);
    };
    cvt(x, x_b, (size_t)MR * DMODEL);
    cvt(W_in, Win_b, (size_t)4096 * 1024);
    k_cvt_wxp<<<(128 * DINNER) / 256, 256, 0, stream>>>(W_xp, Wxp_b);
    cvt(W_dt, Wdt_b, (size_t)DINNER * 64);
    cvt(W_os, Wos_b, (size_t)DMODEL * DINNER);
    cvt(W_o, Wo_b, (size_t)DMODEL * DMODEL);

    // xz = x @ W_in^T   [4096,4096] K=1024
    k_gemm_bt<EPI_F32><<<(MR / 128) * (4096 / 128), 256, 0, stream>>>(
        x_b, Win_b, MR, 4096, 1024, xz, nullptr, nullptr, nullptr, nullptr, nullptr);
    // conv + silu
    k_conv<<<(MR * DINNER) / 256, 256, 0, stream>>>(xz, conv_w, conv_b, xs, xs_b);
    // x_dbl = xs @ W_xp^T (padded N=128), split epilogue
    k_gemm_bt<EPI_SPLIT><<<MR / 128, 256, 0, stream>>>(
        xs_b, Wxp_b, MR, 128, DINNER, nullptr, nullptr, nullptr, dtr_b, Bmf, Cmf);
    // dt = softplus(dtr @ W_dt^T + b_dt)  [4096,2048] K=64
    k_gemm_bt<EPI_SOFTPLUS><<<(MR / 128) * (DINNER / 128), 256, 0, stream>>>(
        dtr_b, Wdt_b, MR, DINNER, 64, dt, nullptr, b_dt, nullptr, nullptr, nullptr);
    // selective scan + gate -> y (bf16)
    k_scan<<<BB * (DINNER / 16), 256, 0, stream>>>(dt, xs, Bmf, Cmf, xz, A_log, Dvec, y_b);
    // y2 = y @ W_out_ssm^T  [4096,1024] K=2048 -> bf16
    k_gemm_bt<EPI_BF16><<<(MR / 128) * (DMODEL / 128), 256, 0, stream>>>(
        y_b, Wos_b, MR, DMODEL, DINNER, nullptr, y2_b, nullptr, nullptr, nullptr, nullptr);
    // out = y2 @ W_out^T + b_out  [4096,1024] K=1024 -> fp32
    k_gemm_bt<EPI_BIAS><<<(MR / 128) * (DMODEL / 128), 256, 0, stream>>>(
        y2_b, Wo_b, MR, DMODEL, 1024, out, nullptr, b_o, nullptr, nullptr, nullptr);
}

// Round 2
// 507.407 us; speedup vs baseline: 3.3137x; 3.3137x over previous
//
#include <hip/hip_runtime.h>
#include <hip/hip_bf16.h>
#include <cmath>
#include <cstdint>

typedef __bf16 bf16_t;
typedef bf16_t bf16x8 __attribute__((ext_vector_type(8)));
typedef bf16_t bf16x4 __attribute__((ext_vector_type(4)));
typedef float f32x4 __attribute__((ext_vector_type(4)));

#define BB 2
#define LL 2048
#define DMODEL 1024
#define DINNER 2048
#define DSTATE 16
#define NC 32      // chunks over L
#define CHUNK 64   // L / NC

// ---------------- fp32 -> bf16 convert (4 elems/thread) ----------------
__global__ void k_cvt4(const float* __restrict__ in, bf16_t* __restrict__ out, int n4) {
    int i = blockIdx.x * 256 + threadIdx.x;
    if (i >= n4) return;
    float4 v = reinterpret_cast<const float4*>(in)[i];
    bf16x4 o;
    o[0] = (bf16_t)v.x; o[1] = (bf16_t)v.y; o[2] = (bf16_t)v.z; o[3] = (bf16_t)v.w;
    reinterpret_cast<bf16x4*>(out)[i] = o;
}

// ---------------- W_xp [96,2048] -> bf16 zero-padded [128,2048] ----------------
__global__ void k_cvt_wxp(const float* __restrict__ in, bf16_t* __restrict__ out) {
    int i = blockIdx.x * 256 + threadIdx.x;   // over 128*2048
    int r = i >> 11, c = i & (DINNER - 1);
    float v = (r < 96) ? in[r * DINNER + c] : 0.f;
    out[i] = (bf16_t)v;
}

// ---------------- async global->LDS helper ----------------
__device__ __forceinline__ void gload16(const void* g, void* l) {
    __builtin_amdgcn_global_load_lds(
        (const __attribute__((address_space(1))) void*)g,
        (__attribute__((address_space(3))) void*)l,
        16, 0, 0);
}

enum { EPI_F32 = 0, EPI_BF16 = 1, EPI_BIAS = 2, EPI_SOFTPLUS = 3, EPI_SPLIT = 4 };

// ---------------- bf16 MFMA GEMM: C[M,N] = A[M,K] @ B[N,K]^T ----------------
// 128x128 tile, BK=32, 256 threads = 4 waves (2x2 of 64x64), 16x16x32 bf16 MFMA.
template <int EPI>
__global__ void k_gemm_bt(const bf16_t* __restrict__ A, const bf16_t* __restrict__ Bt,
                          int M, int N, int K,
                          float* __restrict__ C, bf16_t* __restrict__ Cb,
                          const float* __restrict__ bias,
                          bf16_t* __restrict__ o_dtr, float* __restrict__ o_B,
                          float* __restrict__ o_C) {
    __shared__ bf16_t sA[128 * 32];
    __shared__ bf16_t sB[128 * 32];
    const int tid = threadIdx.x;
    const int wid = tid >> 6, lane = tid & 63;
    const int ntile = N >> 7;
    const int m0 = (blockIdx.x / ntile) << 7;
    const int n0 = (blockIdx.x % ntile) << 7;
    const int wr = wid >> 1, wc = wid & 1;
    f32x4 acc[4][4] = {};

    const bf16_t* ap = A + (size_t)(m0 + (tid >> 2)) * K + (tid & 3) * 8;
    const bf16_t* bp = Bt + (size_t)(n0 + (tid >> 2)) * K + (tid & 3) * 8;
    char* sAd = (char*)sA + wid * 1024;   // wave-uniform LDS dst (lane*16 added by HW)
    char* sBd = (char*)sB + wid * 1024;

    const int lm = lane & 15, lk = (lane >> 4) * 8;
    const bf16_t* rA = sA + (wr * 64 + lm) * 32 + lk;
    const bf16_t* rB = sB + (wc * 64 + lm) * 32 + lk;

    for (int kt = 0; kt < K; kt += 32) {
        __syncthreads();
        gload16(ap + kt, sAd);
        gload16(ap + kt + (size_t)64 * K, sAd + 4096);
        gload16(bp + kt, sBd);
        gload16(bp + kt + (size_t)64 * K, sBd + 4096);
        __syncthreads();
        bf16x8 fa[4], fb[4];
        #pragma unroll
        for (int i = 0; i < 4; ++i) fa[i] = *(const bf16x8*)(rA + i * 16 * 32);
        #pragma unroll
        for (int j = 0; j < 4; ++j) fb[j] = *(const bf16x8*)(rB + j * 16 * 32);
        #pragma unroll
        for (int i = 0; i < 4; ++i)
            #pragma unroll
            for (int j = 0; j < 4; ++j)
                acc[i][j] = __builtin_amdgcn_mfma_f32_16x16x32_bf16(fa[i], fb[j], acc[i][j], 0, 0, 0);
    }

    // C/D layout (m89-verified): col = lane&15, row = (lane>>4)*4 + reg
    const int row0 = m0 + wr * 64 + (lane >> 4) * 4;
    const int col0 = n0 + wc * 64 + lm;
    #pragma unroll
    for (int i = 0; i < 4; ++i) {
        #pragma unroll
        for (int j = 0; j < 4; ++j) {
            #pragma unroll
            for (int r = 0; r < 4; ++r) {
                int row = row0 + i * 16 + r;
                int c = col0 + j * 16;
                float v = acc[i][j][r];
                if (EPI == EPI_F32) {
                    C[(size_t)row * N + c] = v;
                } else if (EPI == EPI_BF16) {
                    Cb[(size_t)row * N + c] = (bf16_t)v;
                } else if (EPI == EPI_BIAS) {
                    C[(size_t)row * N + c] = v + bias[c];
                } else if (EPI == EPI_SOFTPLUS) {
                    float xv = v + bias[c];
                    C[(size_t)row * N + c] = fmaxf(xv, 0.f) + log1pf(__expf(-fabsf(xv)));
                } else {  // EPI_SPLIT: cols [0,64)->dtr bf16, [64,80)->B f32, [80,96)->C f32
                    if (c < 64) o_dtr[(size_t)row * 64 + c] = (bf16_t)v;
                    else if (c < 80) o_B[(size_t)row * 16 + (c - 64)] = v;
                    else if (c < 96) o_C[(size_t)row * 16 + (c - 80)] = v;
                }
            }
        }
    }
}

// ---------------- causal depthwise conv (k=4) + bias + SiLU ----------------
__global__ void k_conv(const float* __restrict__ xz, const float* __restrict__ cw,
                       const float* __restrict__ cb, float* __restrict__ xs,
                       bf16_t* __restrict__ xs_b) {
    int idx = blockIdx.x * 256 + threadIdx.x;   // over B*L*DINNER
    int d = idx & (DINNER - 1);
    int bl = idx >> 11;
    int l = bl & (LL - 1);
    const float* col = xz + (size_t)(bl - l) * (2 * DINNER) + d;  // batch base, xin part
    float acc = cb[d];
    #pragma unroll
    for (int j = 0; j < 4; ++j) {
        int li = l - 3 + j;
        if (li >= 0) acc += cw[d * 4 + j] * col[(size_t)li * (2 * DINNER)];
    }
    float s = acc / (1.f + __expf(-acc));
    xs[idx] = s;
    xs_b[idx] = (bf16_t)s;
}

// ================= chunked selective scan =================
// h_t = dA_t * h_{t-1} + dt*x*B  is linear in h: over a chunk,
// h_end = alpha * h_start + beta.  p1 computes (alpha,beta) per chunk,
// p2 scans chunk states, p3 replays with correct h0 + fused gate/output.
// lane mapping in p1/p3: s = lane&15 (state), c = lane>>4; wave owns 4 channels.

__global__ __launch_bounds__(256) void k_scan_p1(
    const float* __restrict__ dt, const float* __restrict__ xs,
    const float* __restrict__ Bm, const float* __restrict__ A_log,
    float* __restrict__ alpha, float* __restrict__ beta) {
    const int ck = blockIdx.x & (NC - 1);
    const int g  = (blockIdx.x >> 5) & 127;
    const int b  = blockIdx.x >> 12;
    const int tid = threadIdx.x, wave = tid >> 6, lane = tid & 63;
    const int s = lane & 15, c = lane >> 4;
    const int d = g * 16 + wave * 4 + c;

    const float a = -__expf(A_log[d * DSTATE + s]);
    const int t0 = ck * CHUNK;
    const float* dtp = dt + ((size_t)b * LL + t0) * DINNER + d;
    const float* xsp = xs + ((size_t)b * LL + t0) * DINNER + d;
    const float* Bp  = Bm + ((size_t)b * LL + t0) * DSTATE + s;

    float al = 1.f, be = 0.f;
    #pragma unroll 8
    for (int t = 0; t < CHUNK; ++t) {
        float dtv = dtp[(size_t)t * DINNER];
        float xv  = xsp[(size_t)t * DINNER];
        float Bv  = Bp[(size_t)t * DSTATE];
        float dA = __expf(dtv * a);
        al *= dA;
        be = fmaf(be, dA, dtv * xv * Bv);
    }
    const size_t idx = ((size_t)(b * NC + ck)) * (DINNER * DSTATE) + d * DSTATE + s;
    alpha[idx] = al;
    beta[idx] = be;
}

__global__ __launch_bounds__(256) void k_scan_p2(
    const float* __restrict__ alpha, const float* __restrict__ beta,
    float* __restrict__ H) {
    const int gid = blockIdx.x * 256 + threadIdx.x;   // over B*DINNER*16
    const int b = gid >> 15, r = gid & 32767;
    float h = 0.f;
    #pragma unroll
    for (int ck = 0; ck < NC; ++ck) {
        const size_t i = ((size_t)(b * NC + ck)) * 32768 + r;
        H[i] = h;
        h = fmaf(alpha[i], h, beta[i]);
    }
}

__global__ __launch_bounds__(256) void k_scan_p3(
    const float* __restrict__ dt, const float* __restrict__ xs,
    const float* __restrict__ Bm, const float* __restrict__ Cm,
    const float* __restrict__ xz, const float* __restrict__ A_log,
    const float* __restrict__ Dp, const float* __restrict__ H,
    bf16_t* __restrict__ y) {
    const int ck = blockIdx.x & (NC - 1);
    const int g  = (blockIdx.x >> 5) & 127;
    const int b  = blockIdx.x >> 12;
    const int tid = threadIdx.x, wave = tid >> 6, lane = tid & 63;
    const int s = lane & 15, c = lane >> 4;
    const int d = g * 16 + wave * 4 + c;

    const float a = -__expf(A_log[d * DSTATE + s]);
    const float Dd = Dp[d];
    const int t0 = ck * CHUNK;
    const float* dtp = dt + ((size_t)b * LL + t0) * DINNER + d;
    const float* xsp = xs + ((size_t)b * LL + t0) * DINNER + d;
    const float* Bp  = Bm + ((size_t)b * LL + t0) * DSTATE + s;
    const float* Cp  = Cm + ((size_t)b * LL + t0) * DSTATE + s;
    const float* zp  = xz + ((size_t)b * LL + t0) * (2 * DINNER) + DINNER + d;
    bf16_t* yp = y + ((size_t)b * LL + t0) * DINNER + d;

    float h = H[((size_t)(b * NC + ck)) * 32768 + d * DSTATE + s];
    #pragma unroll 4
    for (int t = 0; t < CHUNK; ++t) {
        float dtv = dtp[(size_t)t * DINNER];
        float xv  = xsp[(size_t)t * DINNER];
        float Bv  = Bp[(size_t)t * DSTATE];
        float Cv  = Cp[(size_t)t * DSTATE];
        float dA = __expf(dtv * a);
        h = fmaf(h, dA, dtv * xv * Bv);
        float p = h * Cv;
        p += __shfl_xor(p, 1, 16);
        p += __shfl_xor(p, 2, 16);
        p += __shfl_xor(p, 4, 16);
        p += __shfl_xor(p, 8, 16);
        if (s == 0) {
            float zv = zp[(size_t)t * (2 * DINNER)];
            float yv = (p + xv * Dd) * (zv / (1.f + __expf(-zv)));
            yp[(size_t)t * DINNER] = (bf16_t)yv;
        }
    }
}

extern "C" void kernel_launch(void* const* d_in, const int* in_sizes, int n_in,
                              void* d_out, int out_size, void* d_ws, size_t ws_size,
                              hipStream_t stream) {
    const float* x      = (const float*)d_in[0];
    const float* W_in   = (const float*)d_in[1];
    const float* conv_w = (const float*)d_in[2];
    const float* conv_b = (const float*)d_in[3];
    const float* W_xp   = (const float*)d_in[4];
    const float* W_dt   = (const float*)d_in[5];
    const float* b_dt   = (const float*)d_in[6];
    const float* A_log  = (const float*)d_in[7];
    const float* Dvec   = (const float*)d_in[8];
    const float* W_os   = (const float*)d_in[9];
    const float* W_o    = (const float*)d_in[10];
    const float* b_o    = (const float*)d_in[11];
    float* out = (float*)d_out;

    char* base = (char*)d_ws;
    size_t off = 0;
    auto alloc = [&](size_t bytes) -> char* {
        char* p = base + off;
        off += (bytes + 255) & ~(size_t)255;
        return p;
    };
    const int MR = BB * LL;  // 4096 rows
    float*  xz    = (float*)alloc((size_t)MR * 4096 * 4);
    float*  xs    = (float*)alloc((size_t)MR * DINNER * 4);
    bf16_t* xs_b  = (bf16_t*)alloc((size_t)MR * DINNER * 2);
    float*  dt    = (float*)alloc((size_t)MR * DINNER * 4);
    bf16_t* dtr_b = (bf16_t*)alloc((size_t)MR * 64 * 2);
    float*  Bmf   = (float*)alloc((size_t)MR * 16 * 4);
    float*  Cmf   = (float*)alloc((size_t)MR * 16 * 4);
    bf16_t* y_b   = (bf16_t*)alloc((size_t)MR * DINNER * 2);
    bf16_t* y2_b  = (bf16_t*)alloc((size_t)MR * DMODEL * 2);  // 8 MB
    bf16_t* x_b   = (bf16_t*)alloc((size_t)MR * DMODEL * 2);  // 8 MB
    bf16_t* Win_b = (bf16_t*)alloc((size_t)4096 * 1024 * 2);  // 8 MB
    bf16_t* Wxp_b = (bf16_t*)alloc((size_t)128 * DINNER * 2);
    bf16_t* Wdt_b = (bf16_t*)alloc((size_t)DINNER * 64 * 2);
    bf16_t* Wos_b = (bf16_t*)alloc((size_t)DMODEL * DINNER * 2);
    bf16_t* Wo_b  = (bf16_t*)alloc((size_t)DMODEL * DMODEL * 2);

    // scan scratch (8 MB each) aliases buffers whose lifetime is disjoint:
    // x_b/Win_b are dead after GEMM1 (before p1); y2_b is written only after p3.
    float* alphab = (float*)x_b;
    float* betab  = (float*)Win_b;
    float* Hbuf   = (float*)y2_b;

    auto cvt = [&](const float* src, bf16_t* dst, size_t n) {
        int n4 = (int)(n / 4);
        k_cvt4<<<(n4 + 255) / 256, 256, 0, stream>>>(src, dst, n4);
    };
    cvt(x, x_b, (size_t)MR * DMODEL);
    cvt(W_in, Win_b, (size_t)4096 * 1024);
    k_cvt_wxp<<<(128 * DINNER) / 256, 256, 0, stream>>>(W_xp, Wxp_b);
    cvt(W_dt, Wdt_b, (size_t)DINNER * 64);
    cvt(W_os, Wos_b, (size_t)DMODEL * DINNER);
    cvt(W_o, Wo_b, (size_t)DMODEL * DMODEL);

    // xz = x @ W_in^T   [4096,4096] K=1024
    k_gemm_bt<EPI_F32><<<(MR / 128) * (4096 / 128), 256, 0, stream>>>(
        x_b, Win_b, MR, 4096, 1024, xz, nullptr, nullptr, nullptr, nullptr, nullptr);
    // conv + silu
    k_conv<<<(MR * DINNER) / 256, 256, 0, stream>>>(xz, conv_w, conv_b, xs, xs_b);
    // x_dbl = xs @ W_xp^T (padded N=128), split epilogue
    k_gemm_bt<EPI_SPLIT><<<MR / 128, 256, 0, stream>>>(
        xs_b, Wxp_b, MR, 128, DINNER, nullptr, nullptr, nullptr, dtr_b, Bmf, Cmf);
    // dt = softplus(dtr @ W_dt^T + b_dt)  [4096,2048] K=64
    k_gemm_bt<EPI_SOFTPLUS><<<(MR / 128) * (DINNER / 128), 256, 0, stream>>>(
        dtr_b, Wdt_b, MR, DINNER, 64, dt, nullptr, b_dt, nullptr, nullptr, nullptr);
    // chunked selective scan + gate -> y (bf16)
    k_scan_p1<<<BB * 128 * NC, 256, 0, stream>>>(dt, xs, Bmf, A_log, alphab, betab);
    k_scan_p2<<<(BB * DINNER * DSTATE) / 256, 256, 0, stream>>>(alphab, betab, Hbuf);
    k_scan_p3<<<BB * 128 * NC, 256, 0, stream>>>(dt, xs, Bmf, Cmf, xz, A_log, Dvec, Hbuf, y_b);
    // y2 = y @ W_out_ssm^T  [4096,1024] K=2048 -> bf16
    k_gemm_bt<EPI_BF16><<<(MR / 128) * (DMODEL / 128), 256, 0, stream>>>(
        y_b, Wos_b, MR, DMODEL, DINNER, nullptr, y2_b, nullptr, nullptr, nullptr, nullptr);
    // out = y2 @ W_out^T + b_out  [4096,1024] K=1024 -> fp32
    k_gemm_bt<EPI_BIAS><<<(MR / 128) * (DMODEL / 128), 256, 0, stream>>>(
        y2_b, Wo_b, MR, DMODEL, 1024, out, nullptr, b_o, nullptr, nullptr, nullptr);
}

// Round 4
// 430.559 us; speedup vs baseline: 3.9052x; 1.1785x over previous
//
#include <hip/hip_runtime.h>
#include <hip/hip_bf16.h>
#include <cmath>
#include <cstdint>

typedef __bf16 bf16_t;
typedef bf16_t bf16x8 __attribute__((ext_vector_type(8)));
typedef bf16_t bf16x4 __attribute__((ext_vector_type(4)));
typedef float f32x4 __attribute__((ext_vector_type(4)));

#define BB 2
#define LL 2048
#define DMODEL 1024
#define DINNER 2048
#define DSTATE 16
#define NC 64      // chunks over L
#define CHUNK 32   // L / NC

// fast 2^x via v_exp_f32
#define EXP2F(x) __builtin_amdgcn_exp2f(x)

// ---------------- fp32 -> bf16 convert (4 elems/thread) ----------------
__global__ void k_cvt4(const float* __restrict__ in, bf16_t* __restrict__ out, int n4) {
    int i = blockIdx.x * 256 + threadIdx.x;
    if (i >= n4) return;
    float4 v = reinterpret_cast<const float4*>(in)[i];
    bf16x4 o;
    o[0] = (bf16_t)v.x; o[1] = (bf16_t)v.y; o[2] = (bf16_t)v.z; o[3] = (bf16_t)v.w;
    reinterpret_cast<bf16x4*>(out)[i] = o;
}

// ---------------- W_xp [96,2048] -> bf16 zero-padded [128,2048] ----------------
__global__ void k_cvt_wxp(const float* __restrict__ in, bf16_t* __restrict__ out) {
    int i = blockIdx.x * 256 + threadIdx.x;   // over 128*2048
    int r = i >> 11, c = i & (DINNER - 1);
    float v = (r < 96) ? in[r * DINNER + c] : 0.f;
    out[i] = (bf16_t)v;
}

// ---------------- async global->LDS helper ----------------
__device__ __forceinline__ void gload16(const void* g, void* l) {
    __builtin_amdgcn_global_load_lds(
        (const __attribute__((address_space(1))) void*)g,
        (__attribute__((address_space(3))) void*)l,
        16, 0, 0);
}

enum { EPI_F32 = 0, EPI_BF16 = 1, EPI_BIAS = 2, EPI_SPLIT = 4, EPI_XZ = 5, EPI_SOFTPLUS_T = 6 };

// ---------------- bf16 MFMA GEMM: C[M,N] = A[M,K] @ B[N,K]^T ----------------
// 128x128 tile, BK=32, 256 threads = 4 waves (2x2 of 64x64), 16x16x32 bf16 MFMA.
template <int EPI>
__global__ void k_gemm_bt(const bf16_t* __restrict__ A, const bf16_t* __restrict__ Bt,
                          int M, int N, int K,
                          float* __restrict__ C, bf16_t* __restrict__ Cb,
                          const float* __restrict__ bias,
                          bf16_t* __restrict__ o_dtr, float* __restrict__ o_B,
                          float* __restrict__ o_C) {
    __shared__ bf16_t sA[128 * 32];
    __shared__ bf16_t sB[128 * 32];
    const int tid = threadIdx.x;
    const int wid = tid >> 6, lane = tid & 63;
    const int ntile = N >> 7;
    const int m0 = (blockIdx.x / ntile) << 7;
    const int n0 = (blockIdx.x % ntile) << 7;
    const int wr = wid >> 1, wc = wid & 1;
    f32x4 acc[4][4] = {};

    const bf16_t* ap = A + (size_t)(m0 + (tid >> 2)) * K + (tid & 3) * 8;
    const bf16_t* bp = Bt + (size_t)(n0 + (tid >> 2)) * K + (tid & 3) * 8;
    char* sAd = (char*)sA + wid * 1024;   // wave-uniform LDS dst (lane*16 added by HW)
    char* sBd = (char*)sB + wid * 1024;

    const int lm = lane & 15, lk = (lane >> 4) * 8;
    const bf16_t* rA = sA + (wr * 64 + lm) * 32 + lk;
    const bf16_t* rB = sB + (wc * 64 + lm) * 32 + lk;

    for (int kt = 0; kt < K; kt += 32) {
        __syncthreads();
        gload16(ap + kt, sAd);
        gload16(ap + kt + (size_t)64 * K, sAd + 4096);
        gload16(bp + kt, sBd);
        gload16(bp + kt + (size_t)64 * K, sBd + 4096);
        __syncthreads();
        bf16x8 fa[4], fb[4];
        #pragma unroll
        for (int i = 0; i < 4; ++i) fa[i] = *(const bf16x8*)(rA + i * 16 * 32);
        #pragma unroll
        for (int j = 0; j < 4; ++j) fb[j] = *(const bf16x8*)(rB + j * 16 * 32);
        #pragma unroll
        for (int i = 0; i < 4; ++i)
            #pragma unroll
            for (int j = 0; j < 4; ++j)
                acc[i][j] = __builtin_amdgcn_mfma_f32_16x16x32_bf16(fa[i], fb[j], acc[i][j], 0, 0, 0);
    }

    // C/D layout (m89-verified): col = lane&15, row = (lane>>4)*4 + reg
    const int row0 = m0 + wr * 64 + (lane >> 4) * 4;
    const int col0 = n0 + wc * 64 + lm;
    #pragma unroll
    for (int i = 0; i < 4; ++i) {
        #pragma unroll
        for (int j = 0; j < 4; ++j) {
            #pragma unroll
            for (int r = 0; r < 4; ++r) {
                int row = row0 + i * 16 + r;
                int c = col0 + j * 16;
                float v = acc[i][j][r];
                if (EPI == EPI_F32) {
                    C[(size_t)row * N + c] = v;
                } else if (EPI == EPI_BF16) {
                    Cb[(size_t)row * N + c] = (bf16_t)v;
                } else if (EPI == EPI_BIAS) {
                    C[(size_t)row * N + c] = v + bias[c];
                } else if (EPI == EPI_XZ) {
                    // cols [0,2048): xin [row][c]; cols [2048,4096): z -> silu -> zsT[d][row]
                    if (c < DINNER) {
                        C[(size_t)row * DINNER + c] = v;
                    } else {
                        float sv = v / (1.f + __expf(-v));
                        o_B[(size_t)(c - DINNER) * (BB * LL) + row] = sv;
                    }
                } else if (EPI == EPI_SOFTPLUS_T) {
                    float xv = v + bias[c];
                    float sp = fmaxf(xv, 0.f) + log1pf(__expf(-fabsf(xv)));
                    C[(size_t)c * (BB * LL) + row] = sp;   // dtT[d][row]
                } else {  // EPI_SPLIT: cols [0,64)->dtr bf16, [64,80)->B f32, [80,96)->C f32
                    if (c < 64) o_dtr[(size_t)row * 64 + c] = (bf16_t)v;
                    else if (c < 80) o_B[(size_t)row * 16 + (c - 64)] = v;
                    else if (c < 96) o_C[(size_t)row * 16 + (c - 80)] = v;
                }
            }
        }
    }
}

// ---------------- causal depthwise conv (k=4) + bias + SiLU ----------------
// 64x64 tile; writes xs_b [t][d] bf16 (coalesced) and xsT [d][t] fp32 (LDS transpose).
__global__ __launch_bounds__(256) void k_conv(
    const float* __restrict__ xin, const float* __restrict__ cw,
    const float* __restrict__ cb, bf16_t* __restrict__ xs_b,
    float* __restrict__ xsT) {
    __shared__ float tile[64][65];
    const int tid = threadIdx.x;
    const int d0  = (blockIdx.x & 31) * 64;
    const int bl0 = (blockIdx.x >> 5) * 64;
    const int dl = tid & 63;
    const int d  = d0 + dl;
    const float w0 = cw[d * 4], w1 = cw[d * 4 + 1], w2 = cw[d * 4 + 2], w3 = cw[d * 4 + 3];
    const float bias = cb[d];
    const int l0 = bl0 & (LL - 1);   // tiles never cross a batch boundary
    #pragma unroll 4
    for (int i = 0; i < 16; ++i) {
        const int blr = (tid >> 6) + i * 4;
        const int bl = bl0 + blr;
        const int l  = l0 + blr;
        const float* rp = xin + (size_t)bl * DINNER + d;
        float acc = fmaf(w3, rp[0], bias);
        if (l >= 1) acc = fmaf(w2, rp[-(int)DINNER], acc);
        if (l >= 2) acc = fmaf(w1, rp[-2 * (int)DINNER], acc);
        if (l >= 3) acc = fmaf(w0, rp[-3 * (int)DINNER], acc);
        float sv = acc / (1.f + __expf(-acc));
        xs_b[(size_t)bl * DINNER + d] = (bf16_t)sv;
        tile[dl][blr] = sv;
    }
    __syncthreads();
    const int dr = tid >> 2;
    const int q  = tid & 3;
    float* op = xsT + (size_t)(d0 + dr) * (BB * LL) + bl0 + q * 16;
    #pragma unroll
    for (int k = 0; k < 4; ++k) {
        f32x4 v;
        #pragma unroll
        for (int j = 0; j < 4; ++j) v[j] = tile[dr][q * 16 + k * 4 + j];
        reinterpret_cast<f32x4*>(op)[k] = v;
    }
}

// ================= chunked selective scan, lane-owns-channel =================
// Lane owns channel d, keeps all 16 states in registers. dt/xs/z are [d][t]
// (float4 over t); B/C rows are wave-uniform (scalar-load eligible).

__global__ __launch_bounds__(256) void k_scan_p1(
    const float* __restrict__ dtT, const float* __restrict__ xsT,
    const float* __restrict__ Bm, const float* __restrict__ A_log,
    float* __restrict__ alpha, float* __restrict__ beta) {
    const int db = blockIdx.x & 7;
    const int ck = (blockIdx.x >> 3) & (NC - 1);
    const int b  = blockIdx.x >> 9;
    const int d  = db * 256 + threadIdx.x;
    const int t0 = ck * CHUNK;

    f32x4 a2[4];
    #pragma unroll
    for (int q = 0; q < 4; ++q) {
        f32x4 av = reinterpret_cast<const f32x4*>(A_log + d * 16)[q];
        #pragma unroll
        for (int j = 0; j < 4; ++j) a2[q][j] = -__expf(av[j]) * 1.44269504f;
    }
    const f32x4* dtp = reinterpret_cast<const f32x4*>(dtT + (size_t)d * (BB * LL) + b * LL + t0);
    const f32x4* xsp = reinterpret_cast<const f32x4*>(xsT + (size_t)d * (BB * LL) + b * LL + t0);
    const f32x4* Bp  = reinterpret_cast<const f32x4*>(Bm + ((size_t)b * LL + t0) * 16);

    float al[16], be[16];
    #pragma unroll
    for (int s = 0; s < 16; ++s) { al[s] = 1.f; be[s] = 0.f; }

    #pragma unroll 2
    for (int tq = 0; tq < CHUNK / 4; ++tq) {
        f32x4 dt4 = dtp[tq];
        f32x4 xs4 = xsp[tq];
        #pragma unroll
        for (int tt = 0; tt < 4; ++tt) {
            const int t = tq * 4 + tt;
            f32x4 Bq[4];
            #pragma unroll
            for (int q = 0; q < 4; ++q) Bq[q] = Bp[t * 4 + q];
            float dtv = dt4[tt], xv = xs4[tt];
            float dtx = dtv * xv;
            #pragma unroll
            for (int s = 0; s < 16; ++s) {
                float dA = EXP2F(dtv * a2[s >> 2][s & 3]);
                al[s] *= dA;
                be[s] = fmaf(be[s], dA, dtx * Bq[s >> 2][s & 3]);
            }
        }
    }
    float* ap = alpha + ((size_t)(b * NC + ck)) * (DINNER * 16) + (size_t)d * 16;
    float* bp = beta  + ((size_t)(b * NC + ck)) * (DINNER * 16) + (size_t)d * 16;
    #pragma unroll
    for (int q = 0; q < 4; ++q) {
        f32x4 av, bv;
        #pragma unroll
        for (int j = 0; j < 4; ++j) { av[j] = al[q * 4 + j]; bv[j] = be[q * 4 + j]; }
        reinterpret_cast<f32x4*>(ap)[q] = av;
        reinterpret_cast<f32x4*>(bp)[q] = bv;
    }
}

__global__ __launch_bounds__(256) void k_scan_p2(
    const float* __restrict__ alpha, const float* __restrict__ beta,
    float* __restrict__ H) {
    const int gid = blockIdx.x * 256 + threadIdx.x;   // over B*DINNER*16
    const int b = gid >> 15, r = gid & 32767;
    float h = 0.f;
    #pragma unroll 8
    for (int ck = 0; ck < NC; ++ck) {
        const size_t i = ((size_t)(b * NC + ck)) * 32768 + r;
        H[i] = h;
        h = fmaf(alpha[i], h, beta[i]);
    }
}

__global__ __launch_bounds__(256) void k_scan_p3(
    const float* __restrict__ dtT, const float* __restrict__ xsT,
    const float* __restrict__ Bm, const float* __restrict__ Cm,
    const float* __restrict__ zsT, const float* __restrict__ A_log,
    const float* __restrict__ Dp, const float* __restrict__ H,
    bf16_t* __restrict__ y) {
    const int db = blockIdx.x & 7;
    const int ck = (blockIdx.x >> 3) & (NC - 1);
    const int b  = blockIdx.x >> 9;
    const int d  = db * 256 + threadIdx.x;
    const int t0 = ck * CHUNK;

    f32x4 a2[4];
    #pragma unroll
    for (int q = 0; q < 4; ++q) {
        f32x4 av = reinterpret_cast<const f32x4*>(A_log + d * 16)[q];
        #pragma unroll
        for (int j = 0; j < 4; ++j) a2[q][j] = -__expf(av[j]) * 1.44269504f;
    }
    const float Dd = Dp[d];
    const f32x4* dtp = reinterpret_cast<const f32x4*>(dtT + (size_t)d * (BB * LL) + b * LL + t0);
    const f32x4* xsp = reinterpret_cast<const f32x4*>(xsT + (size_t)d * (BB * LL) + b * LL + t0);
    const f32x4* zp  = reinterpret_cast<const f32x4*>(zsT + (size_t)d * (BB * LL) + b * LL + t0);
    const f32x4* Bp  = reinterpret_cast<const f32x4*>(Bm + ((size_t)b * LL + t0) * 16);
    const f32x4* Cp  = reinterpret_cast<const f32x4*>(Cm + ((size_t)b * LL + t0) * 16);
    bf16_t* yp = y + ((size_t)b * LL + t0) * DINNER + d;

    float h[16];
    {
        const f32x4* hp = reinterpret_cast<const f32x4*>(H + ((size_t)(b * NC + ck)) * 32768 + (size_t)d * 16);
        #pragma unroll
        for (int q = 0; q < 4; ++q) {
            f32x4 hv = hp[q];
            #pragma unroll
            for (int j = 0; j < 4; ++j) h[q * 4 + j] = hv[j];
        }
    }

    #pragma unroll 2
    for (int tq = 0; tq < CHUNK / 4; ++tq) {
        f32x4 dt4 = dtp[tq];
        f32x4 xs4 = xsp[tq];
        f32x4 z4  = zp[tq];
        #pragma unroll
        for (int tt = 0; tt < 4; ++tt) {
            const int t = tq * 4 + tt;
            f32x4 Bq[4], Cq[4];
            #pragma unroll
            for (int q = 0; q < 4; ++q) { Bq[q] = Bp[t * 4 + q]; Cq[q] = Cp[t * 4 + q]; }
            float dtv = dt4[tt], xv = xs4[tt];
            float dtx = dtv * xv;
            float yacc = 0.f;
            #pragma unroll
            for (int s = 0; s < 16; ++s) {
                float dA = EXP2F(dtv * a2[s >> 2][s & 3]);
                h[s] = fmaf(h[s], dA, dtx * Bq[s >> 2][s & 3]);
                yacc = fmaf(h[s], Cq[s >> 2][s & 3], yacc);
            }
            float yv = (yacc + xv * Dd) * z4[tt];   // z already silu'd
            yp[(size_t)t * DINNER] = (bf16_t)yv;
        }
    }
}

extern "C" void kernel_launch(void* const* d_in, const int* in_sizes, int n_in,
                              void* d_out, int out_size, void* d_ws, size_t ws_size,
                              hipStream_t stream) {
    const float* x      = (const float*)d_in[0];
    const float* W_in   = (const float*)d_in[1];
    const float* conv_w = (const float*)d_in[2];
    const float* conv_b = (const float*)d_in[3];
    const float* W_xp   = (const float*)d_in[4];
    const float* W_dt   = (const float*)d_in[5];
    const float* b_dt   = (const float*)d_in[6];
    const float* A_log  = (const float*)d_in[7];
    const float* Dvec   = (const float*)d_in[8];
    const float* W_os   = (const float*)d_in[9];
    const float* W_o    = (const float*)d_in[10];
    const float* b_o    = (const float*)d_in[11];
    float* out = (float*)d_out;

    char* base = (char*)d_ws;
    size_t off = 0;
    auto alloc = [&](size_t bytes) -> char* {
        char* p = base + off;
        off += (bytes + 255) & ~(size_t)255;
        return p;
    };
    const int MR = BB * LL;  // 4096 rows
    // NOTE: x_b, Win_b allocated first and contiguous (16 MiB) -> aliased by beta.
    bf16_t* x_b   = (bf16_t*)alloc((size_t)MR * DMODEL * 2);     // 8 MiB
    bf16_t* Win_b = (bf16_t*)alloc((size_t)4096 * 1024 * 2);     // 8 MiB
    bf16_t* xs_b  = (bf16_t*)alloc((size_t)MR * DINNER * 2);     // 16 MiB
    float*  xin   = (float*)alloc((size_t)MR * DINNER * 4);      // 32 MiB (aliased by alpha)
    float*  zsT   = (float*)alloc((size_t)DINNER * MR * 4);      // 32 MiB
    float*  xsT   = (float*)alloc((size_t)DINNER * MR * 4);      // 32 MiB
    float*  dtT   = (float*)alloc((size_t)DINNER * MR * 4);      // 32 MiB
    float*  Hbuf  = (float*)alloc((size_t)BB * NC * DINNER * 16 * 4);  // 16 MiB
    bf16_t* y_b   = (bf16_t*)alloc((size_t)MR * DINNER * 2);     // 16 MiB
    bf16_t* y2_b  = (bf16_t*)alloc((size_t)MR * DMODEL * 2);     // 8 MiB
    bf16_t* dtr_b = (bf16_t*)alloc((size_t)MR * 64 * 2);
    float*  Bmf   = (float*)alloc((size_t)MR * 16 * 4);
    float*  Cmf   = (float*)alloc((size_t)MR * 16 * 4);
    bf16_t* Wxp_b = (bf16_t*)alloc((size_t)128 * DINNER * 2);
    bf16_t* Wdt_b = (bf16_t*)alloc((size_t)DINNER * 64 * 2);
    bf16_t* Wos_b = (bf16_t*)alloc((size_t)DMODEL * DINNER * 2);
    bf16_t* Wo_b  = (bf16_t*)alloc((size_t)DMODEL * DMODEL * 2);

    // scan scratch aliases (lifetimes disjoint):
    //   alpha -> xin (xin dead after k_conv; p1 runs later)
    //   beta  -> x_b+Win_b (16 MiB exactly; dead after GEMM1)
    float* alphab = (float*)xin;
    float* betab  = (float*)x_b;

    auto cvt = [&](const float* src, bf16_t* dst, size_t n) {
        int n4 = (int)(n / 4);
        k_cvt4<<<(n4 + 255) / 256, 256, 0, stream>>>(src, dst, n4);
    };
    cvt(x, x_b, (size_t)MR * DMODEL);
    cvt(W_in, Win_b, (size_t)4096 * 1024);
    k_cvt_wxp<<<(128 * DINNER) / 256, 256, 0, stream>>>(W_xp, Wxp_b);
    cvt(W_dt, Wdt_b, (size_t)DINNER * 64);
    cvt(W_os, Wos_b, (size_t)DMODEL * DINNER);
    cvt(W_o, Wo_b, (size_t)DMODEL * DMODEL);

    // xz = x @ W_in^T [4096,4096] K=1024; epilogue: xin [t][d], zsT [d][t] silu'd
    k_gemm_bt<EPI_XZ><<<(MR / 128) * (4096 / 128), 256, 0, stream>>>(
        x_b, Win_b, MR, 4096, 1024, xin, nullptr, nullptr, nullptr, zsT, nullptr);
    // conv + silu -> xs_b [t][d] bf16, xsT [d][t] fp32
    k_conv<<<(MR / 64) * (DINNER / 64), 256, 0, stream>>>(xin, conv_w, conv_b, xs_b, xsT);
    // x_dbl = xs @ W_xp^T (padded N=128), split epilogue
    k_gemm_bt<EPI_SPLIT><<<MR / 128, 256, 0, stream>>>(
        xs_b, Wxp_b, MR, 128, DINNER, nullptr, nullptr, nullptr, dtr_b, Bmf, Cmf);
    // dt = softplus(dtr @ W_dt^T + b_dt) -> dtT [d][t] fp32
    k_gemm_bt<EPI_SOFTPLUS_T><<<(MR / 128) * (DINNER / 128), 256, 0, stream>>>(
        dtr_b, Wdt_b, MR, DINNER, 64, dtT, nullptr, b_dt, nullptr, nullptr, nullptr);
    // chunked selective scan + gate -> y (bf16)
    k_scan_p1<<<BB * NC * (DINNER / 256), 256, 0, stream>>>(dtT, xsT, Bmf, A_log, alphab, betab);
    k_scan_p2<<<(BB * DINNER * DSTATE) / 256, 256, 0, stream>>>(alphab, betab, Hbuf);
    k_scan_p3<<<BB * NC * (DINNER / 256), 256, 0, stream>>>(dtT, xsT, Bmf, Cmf, zsT, A_log, Dvec, Hbuf, y_b);
    // y2 = y @ W_out_ssm^T  [4096,1024] K=2048 -> bf16
    k_gemm_bt<EPI_BF16><<<(MR / 128) * (DMODEL / 128), 256, 0, stream>>>(
        y_b, Wos_b, MR, DMODEL, DINNER, nullptr, y2_b, nullptr, nullptr, nullptr, nullptr);
    // out = y2 @ W_out^T + b_out  [4096,1024] K=1024 -> fp32
    k_gemm_bt<EPI_BIAS><<<(MR / 128) * (DMODEL / 128), 256, 0, stream>>>(
        y2_b, Wo_b, MR, DMODEL, 1024, out, nullptr, b_o, nullptr, nullptr, nullptr);
}

// Round 5
// 317.663 us; speedup vs baseline: 5.2931x; 1.3554x over previous
//
#include <hip/hip_runtime.h>
#include <hip/hip_bf16.h>
#include <cmath>
#include <cstdint>

typedef __bf16 bf16_t;
typedef bf16_t bf16x8 __attribute__((ext_vector_type(8)));
typedef bf16_t bf16x4 __attribute__((ext_vector_type(4)));
typedef float f32x4 __attribute__((ext_vector_type(4)));

#define BB 2
#define LL 2048
#define DMODEL 1024
#define DINNER 2048
#define DSTATE 16
#define NC 64      // chunks over L
#define CHUNK 32   // L / NC

// fast 2^x via v_exp_f32
#define EXP2F(x) __builtin_amdgcn_exp2f(x)

// ---------------- fp32 -> bf16 convert (4 elems/thread) ----------------
__global__ void k_cvt4(const float* __restrict__ in, bf16_t* __restrict__ out, int n4) {
    int i = blockIdx.x * 256 + threadIdx.x;
    if (i >= n4) return;
    float4 v = reinterpret_cast<const float4*>(in)[i];
    bf16x4 o;
    o[0] = (bf16_t)v.x; o[1] = (bf16_t)v.y; o[2] = (bf16_t)v.z; o[3] = (bf16_t)v.w;
    reinterpret_cast<bf16x4*>(out)[i] = o;
}

// ---------------- W_xp [96,2048] -> bf16 zero-padded [128,2048] ----------------
__global__ void k_cvt_wxp(const float* __restrict__ in, bf16_t* __restrict__ out) {
    int i = blockIdx.x * 256 + threadIdx.x;   // over 128*2048
    int r = i >> 11, c = i & (DINNER - 1);
    float v = (r < 96) ? in[r * DINNER + c] : 0.f;
    out[i] = (bf16_t)v;
}

// ---------------- async global->LDS helper ----------------
__device__ __forceinline__ void gload16(const void* g, void* l) {
    __builtin_amdgcn_global_load_lds(
        (const __attribute__((address_space(1))) void*)g,
        (__attribute__((address_space(3))) void*)l,
        16, 0, 0);
}

enum { EPI_F32 = 0, EPI_BF16 = 1, EPI_BIAS = 2, EPI_SPLIT = 4, EPI_XZ = 5, EPI_SOFTPLUS_T = 6 };

// ---------------- bf16 MFMA GEMM: C[M,N] = A[M,K] @ B[N,K]^T ----------------
// 128x128 tile, BK=32, 256 threads = 4 waves (2x2 of 64x64), 16x16x32 bf16 MFMA.
template <int EPI>
__global__ void k_gemm_bt(const bf16_t* __restrict__ A, const bf16_t* __restrict__ Bt,
                          int M, int N, int K,
                          float* __restrict__ C, bf16_t* __restrict__ Cb,
                          const float* __restrict__ bias,
                          bf16_t* __restrict__ o_dtr, float* __restrict__ o_B,
                          float* __restrict__ o_C) {
    __shared__ bf16_t sA[128 * 32];
    __shared__ bf16_t sB[128 * 32];
    const int tid = threadIdx.x;
    const int wid = tid >> 6, lane = tid & 63;
    const int ntile = N >> 7;
    const int m0 = (blockIdx.x / ntile) << 7;
    const int n0 = (blockIdx.x % ntile) << 7;
    const int wr = wid >> 1, wc = wid & 1;
    f32x4 acc[4][4] = {};

    const bf16_t* ap = A + (size_t)(m0 + (tid >> 2)) * K + (tid & 3) * 8;
    const bf16_t* bp = Bt + (size_t)(n0 + (tid >> 2)) * K + (tid & 3) * 8;
    char* sAd = (char*)sA + wid * 1024;   // wave-uniform LDS dst (lane*16 added by HW)
    char* sBd = (char*)sB + wid * 1024;

    const int lm = lane & 15, lk = (lane >> 4) * 8;
    const bf16_t* rA = sA + (wr * 64 + lm) * 32 + lk;
    const bf16_t* rB = sB + (wc * 64 + lm) * 32 + lk;

    for (int kt = 0; kt < K; kt += 32) {
        __syncthreads();
        gload16(ap + kt, sAd);
        gload16(ap + kt + (size_t)64 * K, sAd + 4096);
        gload16(bp + kt, sBd);
        gload16(bp + kt + (size_t)64 * K, sBd + 4096);
        __syncthreads();
        bf16x8 fa[4], fb[4];
        #pragma unroll
        for (int i = 0; i < 4; ++i) fa[i] = *(const bf16x8*)(rA + i * 16 * 32);
        #pragma unroll
        for (int j = 0; j < 4; ++j) fb[j] = *(const bf16x8*)(rB + j * 16 * 32);
        #pragma unroll
        for (int i = 0; i < 4; ++i)
            #pragma unroll
            for (int j = 0; j < 4; ++j)
                acc[i][j] = __builtin_amdgcn_mfma_f32_16x16x32_bf16(fa[i], fb[j], acc[i][j], 0, 0, 0);
    }

    // C/D layout (m89-verified): col = lane&15, row = (lane>>4)*4 + reg
    const int row0 = m0 + wr * 64 + (lane >> 4) * 4;
    const int col0 = n0 + wc * 64 + lm;
    #pragma unroll
    for (int i = 0; i < 4; ++i) {
        #pragma unroll
        for (int j = 0; j < 4; ++j) {
            #pragma unroll
            for (int r = 0; r < 4; ++r) {
                int row = row0 + i * 16 + r;
                int c = col0 + j * 16;
                float v = acc[i][j][r];
                if (EPI == EPI_F32) {
                    C[(size_t)row * N + c] = v;
                } else if (EPI == EPI_BF16) {
                    Cb[(size_t)row * N + c] = (bf16_t)v;
                } else if (EPI == EPI_BIAS) {
                    C[(size_t)row * N + c] = v + bias[c];
                } else if (EPI == EPI_XZ) {
                    // cols [0,2048): xin [row][c]; cols [2048,4096): z -> silu -> zsT[d][row] bf16
                    if (c < DINNER) {
                        C[(size_t)row * DINNER + c] = v;
                    } else {
                        float sv = v / (1.f + __expf(-v));
                        o_dtr[(size_t)(c - DINNER) * (BB * LL) + row] = (bf16_t)sv;
                    }
                } else if (EPI == EPI_SOFTPLUS_T) {
                    float xv = v + bias[c];
                    float sp = fmaxf(xv, 0.f) + log1pf(__expf(-fabsf(xv)));
                    C[(size_t)c * (BB * LL) + row] = sp;   // dtT[d][row]
                } else {  // EPI_SPLIT: cols [0,64)->dtr bf16, [64,80)->B f32, [80,96)->C f32
                    if (c < 64) o_dtr[(size_t)row * 64 + c] = (bf16_t)v;
                    else if (c < 80) o_B[(size_t)row * 16 + (c - 64)] = v;
                    else if (c < 96) o_C[(size_t)row * 16 + (c - 80)] = v;
                }
            }
        }
    }
}

// ---------------- causal depthwise conv (k=4) + bias + SiLU ----------------
// 64x64 tile; writes xs_b [t][d] bf16 (coalesced) and xsT [d][t] bf16 (LDS transpose).
__global__ __launch_bounds__(256) void k_conv(
    const float* __restrict__ xin, const float* __restrict__ cw,
    const float* __restrict__ cb, bf16_t* __restrict__ xs_b,
    bf16_t* __restrict__ xsT) {
    __shared__ float tile[64][65];
    const int tid = threadIdx.x;
    const int d0  = (blockIdx.x & 31) * 64;
    const int bl0 = (blockIdx.x >> 5) * 64;
    const int dl = tid & 63;
    const int d  = d0 + dl;
    const float w0 = cw[d * 4], w1 = cw[d * 4 + 1], w2 = cw[d * 4 + 2], w3 = cw[d * 4 + 3];
    const float bias = cb[d];
    const int l0 = bl0 & (LL - 1);   // tiles never cross a batch boundary
    #pragma unroll 4
    for (int i = 0; i < 16; ++i) {
        const int blr = (tid >> 6) + i * 4;
        const int bl = bl0 + blr;
        const int l  = l0 + blr;
        const float* rp = xin + (size_t)bl * DINNER + d;
        float acc = fmaf(w3, rp[0], bias);
        if (l >= 1) acc = fmaf(w2, rp[-(int)DINNER], acc);
        if (l >= 2) acc = fmaf(w1, rp[-2 * (int)DINNER], acc);
        if (l >= 3) acc = fmaf(w0, rp[-3 * (int)DINNER], acc);
        float sv = acc / (1.f + __expf(-acc));
        xs_b[(size_t)bl * DINNER + d] = (bf16_t)sv;
        tile[dl][blr] = sv;
    }
    __syncthreads();
    const int dr = tid >> 2;
    const int q  = tid & 3;
    bf16_t* op = xsT + (size_t)(d0 + dr) * (BB * LL) + bl0 + q * 16;
    bf16x8 v0, v1;
    #pragma unroll
    for (int j = 0; j < 8; ++j) v0[j] = (bf16_t)tile[dr][q * 16 + j];
    #pragma unroll
    for (int j = 0; j < 8; ++j) v1[j] = (bf16_t)tile[dr][q * 16 + 8 + j];
    reinterpret_cast<bf16x8*>(op)[0] = v0;
    reinterpret_cast<bf16x8*>(op)[1] = v1;
}

// ================= chunked selective scan, lane-owns-channel =================
// Lane owns channel d, keeps all 16 states in registers. dt [d][t] f32,
// xs/z [d][t] bf16 (all chunk loads prefetched to registers); B/C rows
// staged to LDS once per block and broadcast-read.

__global__ __launch_bounds__(256) void k_scan_p1(
    const float* __restrict__ dtT, const bf16_t* __restrict__ xsT,
    const float* __restrict__ Bm, const float* __restrict__ A_log,
    float* __restrict__ alpha, float* __restrict__ beta) {
    __shared__ float sB[CHUNK * 16];   // 2 KB
    const int db = blockIdx.x & 7;
    const int ck = (blockIdx.x >> 3) & (NC - 1);
    const int b  = blockIdx.x >> 9;
    const int tid = threadIdx.x;
    const int d  = db * 256 + tid;
    const int t0 = ck * CHUNK;

    // stage B chunk (coalesced)
    const float* Bsrc = Bm + ((size_t)b * LL + t0) * 16;
    sB[tid] = Bsrc[tid];
    sB[tid + 256] = Bsrc[tid + 256];

    f32x4 a2[4];
    #pragma unroll
    for (int q = 0; q < 4; ++q) {
        f32x4 av = reinterpret_cast<const f32x4*>(A_log + d * 16)[q];
        #pragma unroll
        for (int j = 0; j < 4; ++j) a2[q][j] = -__expf(av[j]) * 1.44269504f;
    }
    const f32x4*  dtp = reinterpret_cast<const f32x4*>(dtT + (size_t)d * (BB * LL) + b * LL + t0);
    const bf16x8* xsp = reinterpret_cast<const bf16x8*>(xsT + (size_t)d * (BB * LL) + b * LL + t0);

    // prefetch whole chunk into registers
    f32x4 dtl[8];
    bf16x8 xsl[4];
    #pragma unroll
    for (int q = 0; q < 8; ++q) dtl[q] = dtp[q];
    #pragma unroll
    for (int q = 0; q < 4; ++q) xsl[q] = xsp[q];

    __syncthreads();

    float al[16], be[16];
    #pragma unroll
    for (int s = 0; s < 16; ++s) { al[s] = 1.f; be[s] = 0.f; }

    #pragma unroll
    for (int t = 0; t < CHUNK; ++t) {
        float dtv = dtl[t >> 2][t & 3];
        float xv  = (float)xsl[t >> 3][t & 7];
        float dtx = dtv * xv;
        #pragma unroll
        for (int q = 0; q < 4; ++q) {
            f32x4 Bq = *reinterpret_cast<const f32x4*>(sB + t * 16 + q * 4);
            #pragma unroll
            for (int j = 0; j < 4; ++j) {
                const int s = q * 4 + j;
                float dA = EXP2F(dtv * a2[q][j]);
                al[s] *= dA;
                be[s] = fmaf(be[s], dA, dtx * Bq[j]);
            }
        }
    }
    float* ap = alpha + ((size_t)(b * NC + ck)) * (DINNER * 16) + (size_t)d * 16;
    float* bp = beta  + ((size_t)(b * NC + ck)) * (DINNER * 16) + (size_t)d * 16;
    #pragma unroll
    for (int q = 0; q < 4; ++q) {
        f32x4 av, bv;
        #pragma unroll
        for (int j = 0; j < 4; ++j) { av[j] = al[q * 4 + j]; bv[j] = be[q * 4 + j]; }
        reinterpret_cast<f32x4*>(ap)[q] = av;
        reinterpret_cast<f32x4*>(bp)[q] = bv;
    }
}

__global__ __launch_bounds__(256) void k_scan_p2(
    const float* __restrict__ alpha, const float* __restrict__ beta,
    float* __restrict__ H) {
    const int gid = blockIdx.x * 256 + threadIdx.x;   // over B*DINNER*16
    const int b = gid >> 15, r = gid & 32767;
    float h = 0.f;
    #pragma unroll 8
    for (int ck = 0; ck < NC; ++ck) {
        const size_t i = ((size_t)(b * NC + ck)) * 32768 + r;
        H[i] = h;
        h = fmaf(alpha[i], h, beta[i]);
    }
}

__global__ __launch_bounds__(256) void k_scan_p3(
    const float* __restrict__ dtT, const bf16_t* __restrict__ xsT,
    const float* __restrict__ Bm, const float* __restrict__ Cm,
    const bf16_t* __restrict__ zsT, const float* __restrict__ A_log,
    const float* __restrict__ Dp, const float* __restrict__ H,
    bf16_t* __restrict__ y) {
    __shared__ float sB[CHUNK * 16];   // 2 KB
    __shared__ float sC[CHUNK * 16];   // 2 KB
    const int db = blockIdx.x & 7;
    const int ck = (blockIdx.x >> 3) & (NC - 1);
    const int b  = blockIdx.x >> 9;
    const int tid = threadIdx.x;
    const int d  = db * 256 + tid;
    const int t0 = ck * CHUNK;

    const float* Bsrc = Bm + ((size_t)b * LL + t0) * 16;
    const float* Csrc = Cm + ((size_t)b * LL + t0) * 16;
    sB[tid] = Bsrc[tid];
    sB[tid + 256] = Bsrc[tid + 256];
    sC[tid] = Csrc[tid];
    sC[tid + 256] = Csrc[tid + 256];

    f32x4 a2[4];
    #pragma unroll
    for (int q = 0; q < 4; ++q) {
        f32x4 av = reinterpret_cast<const f32x4*>(A_log + d * 16)[q];
        #pragma unroll
        for (int j = 0; j < 4; ++j) a2[q][j] = -__expf(av[j]) * 1.44269504f;
    }
    const float Dd = Dp[d];
    const f32x4*  dtp = reinterpret_cast<const f32x4*>(dtT + (size_t)d * (BB * LL) + b * LL + t0);
    const bf16x8* xsp = reinterpret_cast<const bf16x8*>(xsT + (size_t)d * (BB * LL) + b * LL + t0);
    const bf16x8* zp  = reinterpret_cast<const bf16x8*>(zsT + (size_t)d * (BB * LL) + b * LL + t0);
    bf16_t* yp = y + ((size_t)b * LL + t0) * DINNER + d;

    // prefetch whole chunk
    f32x4 dtl[8];
    bf16x8 xsl[4], zsl[4];
    #pragma unroll
    for (int q = 0; q < 8; ++q) dtl[q] = dtp[q];
    #pragma unroll
    for (int q = 0; q < 4; ++q) xsl[q] = xsp[q];
    #pragma unroll
    for (int q = 0; q < 4; ++q) zsl[q] = zp[q];

    float h[16];
    {
        const f32x4* hp = reinterpret_cast<const f32x4*>(H + ((size_t)(b * NC + ck)) * 32768 + (size_t)d * 16);
        #pragma unroll
        for (int q = 0; q < 4; ++q) {
            f32x4 hv = hp[q];
            #pragma unroll
            for (int j = 0; j < 4; ++j) h[q * 4 + j] = hv[j];
        }
    }

    __syncthreads();

    #pragma unroll
    for (int t = 0; t < CHUNK; ++t) {
        float dtv = dtl[t >> 2][t & 3];
        float xv  = (float)xsl[t >> 3][t & 7];
        float zv  = (float)zsl[t >> 3][t & 7];
        float dtx = dtv * xv;
        float yacc = 0.f;
        #pragma unroll
        for (int q = 0; q < 4; ++q) {
            f32x4 Bq = *reinterpret_cast<const f32x4*>(sB + t * 16 + q * 4);
            f32x4 Cq = *reinterpret_cast<const f32x4*>(sC + t * 16 + q * 4);
            #pragma unroll
            for (int j = 0; j < 4; ++j) {
                const int s = q * 4 + j;
                float dA = EXP2F(dtv * a2[q][j]);
                h[s] = fmaf(h[s], dA, dtx * Bq[j]);
                yacc = fmaf(h[s], Cq[j], yacc);
            }
        }
        float yv = (yacc + xv * Dd) * zv;   // z already silu'd
        yp[(size_t)t * DINNER] = (bf16_t)yv;
    }
}

extern "C" void kernel_launch(void* const* d_in, const int* in_sizes, int n_in,
                              void* d_out, int out_size, void* d_ws, size_t ws_size,
                              hipStream_t stream) {
    const float* x      = (const float*)d_in[0];
    const float* W_in   = (const float*)d_in[1];
    const float* conv_w = (const float*)d_in[2];
    const float* conv_b = (const float*)d_in[3];
    const float* W_xp   = (const float*)d_in[4];
    const float* W_dt   = (const float*)d_in[5];
    const float* b_dt   = (const float*)d_in[6];
    const float* A_log  = (const float*)d_in[7];
    const float* Dvec   = (const float*)d_in[8];
    const float* W_os   = (const float*)d_in[9];
    const float* W_o    = (const float*)d_in[10];
    const float* b_o    = (const float*)d_in[11];
    float* out = (float*)d_out;

    char* base = (char*)d_ws;
    size_t off = 0;
    auto alloc = [&](size_t bytes) -> char* {
        char* p = base + off;
        off += (bytes + 255) & ~(size_t)255;
        return p;
    };
    const int MR = BB * LL;  // 4096 rows
    // NOTE: x_b, Win_b allocated first and contiguous (16 MiB) -> aliased by beta.
    bf16_t* x_b   = (bf16_t*)alloc((size_t)MR * DMODEL * 2);     // 8 MiB
    bf16_t* Win_b = (bf16_t*)alloc((size_t)4096 * 1024 * 2);     // 8 MiB
    bf16_t* xs_b  = (bf16_t*)alloc((size_t)MR * DINNER * 2);     // 16 MiB
    float*  xin   = (float*)alloc((size_t)MR * DINNER * 4);      // 32 MiB (aliased by alpha)
    bf16_t* zsT   = (bf16_t*)alloc((size_t)DINNER * MR * 2);     // 16 MiB
    bf16_t* xsT   = (bf16_t*)alloc((size_t)DINNER * MR * 2);     // 16 MiB
    float*  dtT   = (float*)alloc((size_t)DINNER * MR * 4);      // 32 MiB
    float*  Hbuf  = (float*)alloc((size_t)BB * NC * DINNER * 16 * 4);  // 16 MiB
    bf16_t* y_b   = (bf16_t*)alloc((size_t)MR * DINNER * 2);     // 16 MiB
    bf16_t* y2_b  = (bf16_t*)alloc((size_t)MR * DMODEL * 2);     // 8 MiB
    bf16_t* dtr_b = (bf16_t*)alloc((size_t)MR * 64 * 2);
    float*  Bmf   = (float*)alloc((size_t)MR * 16 * 4);
    float*  Cmf   = (float*)alloc((size_t)MR * 16 * 4);
    bf16_t* Wxp_b = (bf16_t*)alloc((size_t)128 * DINNER * 2);
    bf16_t* Wdt_b = (bf16_t*)alloc((size_t)DINNER * 64 * 2);
    bf16_t* Wos_b = (bf16_t*)alloc((size_t)DMODEL * DINNER * 2);
    bf16_t* Wo_b  = (bf16_t*)alloc((size_t)DMODEL * DMODEL * 2);

    // scan scratch aliases (lifetimes disjoint):
    //   alpha -> xin (xin dead after k_conv; p1 runs later)
    //   beta  -> x_b+Win_b (16 MiB exactly; dead after GEMM1)
    float* alphab = (float*)xin;
    float* betab  = (float*)x_b;

    auto cvt = [&](const float* src, bf16_t* dst, size_t n) {
        int n4 = (int)(n / 4);
        k_cvt4<<<(n4 + 255) / 256, 256, 0, stream>>>(src, dst, n4);
    };
    cvt(x, x_b, (size_t)MR * DMODEL);
    cvt(W_in, Win_b, (size_t)4096 * 1024);
    k_cvt_wxp<<<(128 * DINNER) / 256, 256, 0, stream>>>(W_xp, Wxp_b);
    cvt(W_dt, Wdt_b, (size_t)DINNER * 64);
    cvt(W_os, Wos_b, (size_t)DMODEL * DINNER);
    cvt(W_o, Wo_b, (size_t)DMODEL * DMODEL);

    // xz = x @ W_in^T [4096,4096] K=1024; epilogue: xin [t][d] f32, zsT [d][t] bf16 silu'd
    k_gemm_bt<EPI_XZ><<<(MR / 128) * (4096 / 128), 256, 0, stream>>>(
        x_b, Win_b, MR, 4096, 1024, xin, nullptr, nullptr, zsT, nullptr, nullptr);
    // conv + silu -> xs_b [t][d] bf16, xsT [d][t] bf16
    k_conv<<<(MR / 64) * (DINNER / 64), 256, 0, stream>>>(xin, conv_w, conv_b, xs_b, xsT);
    // x_dbl = xs @ W_xp^T (padded N=128), split epilogue
    k_gemm_bt<EPI_SPLIT><<<MR / 128, 256, 0, stream>>>(
        xs_b, Wxp_b, MR, 128, DINNER, nullptr, nullptr, nullptr, dtr_b, Bmf, Cmf);
    // dt = softplus(dtr @ W_dt^T + b_dt) -> dtT [d][t] fp32
    k_gemm_bt<EPI_SOFTPLUS_T><<<(MR / 128) * (DINNER / 128), 256, 0, stream>>>(
        dtr_b, Wdt_b, MR, DINNER, 64, dtT, nullptr, b_dt, nullptr, nullptr, nullptr);
    // chunked selective scan + gate -> y (bf16)
    k_scan_p1<<<BB * NC * (DINNER / 256), 256, 0, stream>>>(dtT, xsT, Bmf, A_log, alphab, betab);
    k_scan_p2<<<(BB * DINNER * DSTATE) / 256, 256, 0, stream>>>(alphab, betab, Hbuf);
    k_scan_p3<<<BB * NC * (DINNER / 256), 256, 0, stream>>>(dtT, xsT, Bmf, Cmf, zsT, A_log, Dvec, Hbuf, y_b);
    // y2 = y @ W_out_ssm^T  [4096,1024] K=2048 -> bf16
    k_gemm_bt<EPI_BF16><<<(MR / 128) * (DMODEL / 128), 256, 0, stream>>>(
        y_b, Wos_b, MR, DMODEL, DINNER, nullptr, y2_b, nullptr, nullptr, nullptr, nullptr);
    // out = y2 @ W_out^T + b_out  [4096,1024] K=1024 -> fp32
    k_gemm_bt<EPI_BIAS><<<(MR / 128) * (DMODEL / 128), 256, 0, stream>>>(
        y2_b, Wo_b, MR, DMODEL, 1024, out, nullptr, b_o, nullptr, nullptr, nullptr);
}